// Round 4
// baseline (327.057 us; speedup 1.0000x reference)
//
#include <hip/hip_runtime.h>
#include <cstdint>
#include <cstddef>

// Problem constants
#define NHEAD 9
#define CHN   256
#define NB    8
#define WH    48
#define SS    2304            // 48*48
#define OUT0  4718592         // 8*256*48*48
// probs region: 47,775,744 floats after OUT0

typedef short bf16x8 __attribute__((ext_vector_type(8)));
typedef float f32x4  __attribute__((ext_vector_type(4)));

__device__ __forceinline__ float bf2f(unsigned int u16) {
    union { unsigned int i; float f; } v; v.i = u16 << 16; return v.f;
}
__device__ __forceinline__ unsigned short f2bf(float f) {
    union { float f; unsigned int i; } v; v.f = f;
    unsigned int x = v.i;
    unsigned int r = x + 0x7fffu + ((x >> 16) & 1u);   // RNE
    return (unsigned short)(r >> 16);
}

// ---------------------------------------------------------------------------
// K1 (fused pre-pass): blocks 0..107 = softmax init (4 rows/block),
// 108..395 = Wv pack, 396..2443 = hs pack.  256 thr.
// ---------------------------------------------------------------------------
__global__ __launch_bounds__(256) void k_pre(const float* __restrict__ centers,
                                             const float* __restrict__ spreads,
                                             const float* __restrict__ hs,
                                             const float* __restrict__ Wv,
                                             float* __restrict__ p1, float* __restrict__ p2,
                                             unsigned short* __restrict__ p1b,
                                             unsigned short* __restrict__ p2b,
                                             unsigned short* __restrict__ hsb,
                                             unsigned short* __restrict__ WF) {
    int blk = blockIdx.x;
    int t = threadIdx.x;
    if (blk < 108) {
        // --- softmax init: p1/p2 fp32 + bf16 zero-padded-to-64 ---
        int lane = t & 63, wave = t >> 6;
        int ridx = blk * 4 + wave;          // 0..431
        int h = ridx / 48, r = ridx % 48;
        float a = spreads[h]; a = a * a;
        float mu1 = centers[2 * h + 0];
        float mu2 = centers[2 * h + 1];
        bool act = lane < 48;
        float dx = (float)(lane - r);
        float q  = -0.5f * a * dx * dx;
        float g1 = act ? (a * mu1 * dx + q) : -INFINITY;
        float g2 = act ? (a * mu2 * dx + q) : -INFINITY;
        float m1 = g1, m2 = g2;
        #pragma unroll
        for (int off = 32; off >= 1; off >>= 1) {
            m1 = fmaxf(m1, __shfl_xor(m1, off));
            m2 = fmaxf(m2, __shfl_xor(m2, off));
        }
        float e1 = act ? expf(g1 - m1) : 0.f;
        float e2 = act ? expf(g2 - m2) : 0.f;
        float s1 = e1, s2 = e2;
        #pragma unroll
        for (int off = 32; off >= 1; off >>= 1) {
            s1 += __shfl_xor(s1, off);
            s2 += __shfl_xor(s2, off);
        }
        float v1 = e1 / s1, v2 = e2 / s2;
        if (act) {
            p1[h * SS + r * 48 + lane] = v1;
            p2[h * SS + r * 48 + lane] = v2;
        }
        p1b[(h * 48 + r) * 64 + lane] = act ? f2bf(v1) : 0;
        p2b[(h * 48 + r) * 64 + lane] = act ? f2bf(v2) : 0;
    } else if (blk < 396) {
        // --- Wv fp32 [e][k] -> WF bf16 [kb][e][kk] ---
        int kb = blk - 108;
        int e  = t;
        const float* src = Wv + (size_t)e * 2304 + kb * 8;
        float4 f0 = *(const float4*)src;
        float4 f1 = *(const float4*)(src + 4);
        uint4 o;
        o.x = (unsigned int)f2bf(f0.x) | ((unsigned int)f2bf(f0.y) << 16);
        o.y = (unsigned int)f2bf(f0.z) | ((unsigned int)f2bf(f0.w) << 16);
        o.z = (unsigned int)f2bf(f1.x) | ((unsigned int)f2bf(f1.y) << 16);
        o.w = (unsigned int)f2bf(f1.z) | ((unsigned int)f2bf(f1.w) << 16);
        *(uint4*)(WF + ((size_t)kb * 256 + e) * 8) = o;
    } else {
        // --- hs fp32 [bd][l][48] -> hsb bf16 [bd][l][64] (zero-padded) ---
        int bd = blk - 396;
        const float* src = hs + (size_t)bd * SS;
        unsigned short* dst = hsb + (size_t)bd * 3072;
        for (int u = t; u < 384; u += 256) {
            int l = u >> 3, c8 = u & 7;
            uint4 o = {0u, 0u, 0u, 0u};
            if (c8 < 6) {
                const float* p = src + l * 48 + c8 * 8;
                float4 f0 = *(const float4*)p;
                float4 f1 = *(const float4*)(p + 4);
                o.x = (unsigned int)f2bf(f0.x) | ((unsigned int)f2bf(f0.y) << 16);
                o.y = (unsigned int)f2bf(f0.z) | ((unsigned int)f2bf(f0.w) << 16);
                o.z = (unsigned int)f2bf(f1.x) | ((unsigned int)f2bf(f1.y) << 16);
                o.w = (unsigned int)f2bf(f1.z) | ((unsigned int)f2bf(f1.w) << 16);
            }
            *(uint4*)(dst + l * 64 + c8 * 8) = o;
        }
    }
}

// ---------------------------------------------------------------------------
// K2 (fused attention apply + probs writer):
// blocks [0, nAttn): per (h, bd-octet):  S = p1*X^T (mfma), V^T = S*p2^T (mfma),
//   packed into AF[b][kb][m][kk] (gemmC A-frag layout).
// blocks [nAttn, ...): pure-BW probs writer, 8 (i,j,h) tiles/block,
//   nontemporal stores (don't evict AF from L3 before gemmC reads it).
// ---------------------------------------------------------------------------
__global__ __launch_bounds__(256, 2) void k_attn_probs(const unsigned short* __restrict__ hsb,
                                                       const unsigned short* __restrict__ p1b,
                                                       const unsigned short* __restrict__ p2b,
                                                       unsigned short* __restrict__ AF,
                                                       const float* __restrict__ p1,
                                                       const float* __restrict__ p2,
                                                       float* __restrict__ probs,
                                                       int nAttn) {
    int blk = blockIdx.x;
    int t = threadIdx.x;

    if (blk < nAttn) {
        __shared__ unsigned short Sbuf[4 * 3456];   // per-wave: 48 x 72 (pitch) bf16
        __shared__ unsigned short Vbuf[8 * 2304];   // [kk][m]

        int h = blk >> 8;
        int rem = blk & 255;
        int b = rem >> 5, od = rem & 31;
        int d0 = od * 8;
        int kb = h * 32 + od;

        int lane = t & 63, wave = t >> 6;
        int l15 = lane & 15, quad = lane >> 4;

        const bf16x8* P1 = (const bf16x8*)(p1b + (size_t)h * 3072);
        const bf16x8* P2 = (const bf16x8*)(p2b + (size_t)h * 3072);
        bf16x8 pa[3][2], pb[3][2];
        #pragma unroll
        for (int tt = 0; tt < 3; ++tt)
            #pragma unroll
            for (int kt = 0; kt < 2; ++kt) {
                int u = (tt * 16 + l15) * 8 + kt * 4 + quad;
                pa[tt][kt] = P1[u];
                pb[tt][kt] = P2[u];
            }

        unsigned short* Sw = Sbuf + wave * 3456;
        for (int z = lane; z < 384; z += 64) {
            int row = z >> 3;
            *(unsigned int*)(Sw + row * 72 + 48 + ((z & 7) << 1)) = 0u;
        }

        for (int s = 0; s < 2; ++s) {
            int d = d0 + wave * 2 + s;
            int kk = wave * 2 + s;
            size_t bd = (size_t)b * 256 + d;
            const bf16x8* X = (const bf16x8*)(hsb + bd * 3072);

            bf16x8 bx[3][2];
            #pragma unroll
            for (int lt = 0; lt < 3; ++lt)
                #pragma unroll
                for (int kt = 0; kt < 2; ++kt)
                    bx[lt][kt] = X[(lt * 16 + l15) * 8 + kt * 4 + quad];

            f32x4 a1[9];
            #pragma unroll
            for (int q = 0; q < 9; ++q) a1[q] = (f32x4){0.f, 0.f, 0.f, 0.f};
            #pragma unroll
            for (int it = 0; it < 3; ++it)
                #pragma unroll
                for (int lt = 0; lt < 3; ++lt) {
                    a1[it * 3 + lt] = __builtin_amdgcn_mfma_f32_16x16x32_bf16(
                        pa[it][0], bx[lt][0], a1[it * 3 + lt], 0, 0, 0);
                    a1[it * 3 + lt] = __builtin_amdgcn_mfma_f32_16x16x32_bf16(
                        pa[it][1], bx[lt][1], a1[it * 3 + lt], 0, 0, 0);
                }

            #pragma unroll
            for (int it = 0; it < 3; ++it)
                #pragma unroll
                for (int lt = 0; lt < 3; ++lt)
                    #pragma unroll
                    for (int r = 0; r < 4; ++r)
                        Sw[(it * 16 + quad * 4 + r) * 72 + lt * 16 + l15] =
                            f2bf(a1[it * 3 + lt][r]);

            bf16x8 a2f[3][2];
            #pragma unroll
            for (int it = 0; it < 3; ++it)
                #pragma unroll
                for (int kt = 0; kt < 2; ++kt)
                    a2f[it][kt] = *(const bf16x8*)(Sw + (it * 16 + l15) * 72 + kt * 32 + quad * 8);

            f32x4 a2[9];
            #pragma unroll
            for (int q = 0; q < 9; ++q) a2[q] = (f32x4){0.f, 0.f, 0.f, 0.f};
            #pragma unroll
            for (int it = 0; it < 3; ++it)
                #pragma unroll
                for (int jt = 0; jt < 3; ++jt) {
                    a2[it * 3 + jt] = __builtin_amdgcn_mfma_f32_16x16x32_bf16(
                        a2f[it][0], pb[jt][0], a2[it * 3 + jt], 0, 0, 0);
                    a2[it * 3 + jt] = __builtin_amdgcn_mfma_f32_16x16x32_bf16(
                        a2f[it][1], pb[jt][1], a2[it * 3 + jt], 0, 0, 0);
                }

            #pragma unroll
            for (int it = 0; it < 3; ++it)
                #pragma unroll
                for (int jt = 0; jt < 3; ++jt) {
                    f32x4 v = a2[it * 3 + jt];
                    unsigned int lo = (unsigned int)f2bf(v[0]) | ((unsigned int)f2bf(v[1]) << 16);
                    unsigned int hi = (unsigned int)f2bf(v[2]) | ((unsigned int)f2bf(v[3]) << 16);
                    int m = (jt * 16 + l15) * 48 + it * 16 + quad * 4;
                    uint2 u2; u2.x = lo; u2.y = hi;
                    *(uint2*)(Vbuf + kk * 2304 + m) = u2;
                }
        }

        __syncthreads();

        const uint2* Vr = (const uint2*)Vbuf;
        uint4* AFq = (uint4*)AF;
        size_t abase = (size_t)(b * 288 + kb) * 2304;
        for (int g = t; g < 576; g += 256) {
            uint2 rk[8];
            #pragma unroll
            for (int kk = 0; kk < 8; ++kk) rk[kk] = Vr[kk * 576 + g];
            #pragma unroll
            for (int mi = 0; mi < 4; ++mi) {
                unsigned int sel = (mi & 1) ? 0x07060302u : 0x05040100u;
                uint4 o;
                if (mi < 2) {
                    o.x = __builtin_amdgcn_perm(rk[1].x, rk[0].x, sel);
                    o.y = __builtin_amdgcn_perm(rk[3].x, rk[2].x, sel);
                    o.z = __builtin_amdgcn_perm(rk[5].x, rk[4].x, sel);
                    o.w = __builtin_amdgcn_perm(rk[7].x, rk[6].x, sel);
                } else {
                    o.x = __builtin_amdgcn_perm(rk[1].y, rk[0].y, sel);
                    o.y = __builtin_amdgcn_perm(rk[3].y, rk[2].y, sel);
                    o.z = __builtin_amdgcn_perm(rk[5].y, rk[4].y, sel);
                    o.w = __builtin_amdgcn_perm(rk[7].y, rk[6].y, sel);
                }
                AFq[abase + g * 4 + mi] = o;
            }
        }
    } else {
        // --- probs writer: probs[idx][k*48+l] = p1[h,i,k]*p2[h,j,l], idx=(i*48+j)*9+h
        int pb = blk - nAttn;
        __shared__ float pr1[48];
        __shared__ float4 pr2[12];
        for (int tt = 0; tt < 8; ++tt) {
            int idx = pb * 8 + tt;
            int h = idx % 9; int ij = idx / 9; int j = ij % 48; int i = ij / 48;
            __syncthreads();
            if (t < 48) pr1[t] = p1[(h * 48 + i) * 48 + t];
            else if (t < 60) pr2[t - 48] = ((const float4*)(p2 + (h * 48 + j) * 48))[t - 48];
            __syncthreads();
            f32x4* op = (f32x4*)(probs + (size_t)idx * SS);
            for (int g = t; g < 576; g += 256) {
                int e4 = g * 4;
                int k = e4 / 48, l = e4 % 48;
                float s = pr1[k];
                float4 qv = pr2[l >> 2];
                f32x4 v; v[0] = s * qv.x; v[1] = s * qv.y; v[2] = s * qv.z; v[3] = s * qv.w;
                __builtin_nontemporal_store(v, op + g);
            }
        }
    }
}

// ---------------------------------------------------------------------------
// K3 (GEMM-C, MFMA): out[b][e][m] = sum_k AF(k,m)*W(e,k) + vb[e]
// grid: 576 = b*72 + mb*2 + nbk, 256 thr, no LDS, no barriers
// ---------------------------------------------------------------------------
__global__ __launch_bounds__(256) void k_gemmC(const unsigned short* __restrict__ AF,
                                               const unsigned short* __restrict__ WF,
                                               const float* __restrict__ vb,
                                               float* __restrict__ out) {
    int blk = blockIdx.x;
    int b = blk / 72; int r = blk % 72; int mb = r >> 1; int nbk = r & 1;
    int t = threadIdx.x;
    int lane = t & 63, wave = t >> 6;
    int l15 = lane & 15, quad = lane >> 4;
    int wm = wave & 1, we = wave >> 1;
    int m0 = mb * 64 + wm * 32;
    int e0 = nbk * 128 + we * 64;

    const bf16x8* pa = (const bf16x8*)AF + (size_t)b * 288 * 2304
                       + (size_t)quad * 2304 + m0 + l15;
    const bf16x8* pw = (const bf16x8*)WF + (size_t)quad * 256 + e0 + l15;

    f32x4 acc[2][4];
    #pragma unroll
    for (int i = 0; i < 2; i++)
        #pragma unroll
        for (int j = 0; j < 4; j++) acc[i][j] = (f32x4){0.f, 0.f, 0.f, 0.f};

    bf16x8 a_cur[2], w_cur[4], a_nxt[2], w_nxt[4];
    a_cur[0] = pa[0];  a_cur[1] = pa[16];
    w_cur[0] = pw[0];  w_cur[1] = pw[16]; w_cur[2] = pw[32]; w_cur[3] = pw[48];

    for (int c = 0; c < 72; ++c) {
        if (c < 71) {
            a_nxt[0] = pa[9216];      a_nxt[1] = pa[9216 + 16];
            w_nxt[0] = pw[1024];      w_nxt[1] = pw[1024 + 16];
            w_nxt[2] = pw[1024 + 32]; w_nxt[3] = pw[1024 + 48];
        }
        #pragma unroll
        for (int tm = 0; tm < 2; ++tm)
            #pragma unroll
            for (int te = 0; te < 4; ++te)
                acc[tm][te] = __builtin_amdgcn_mfma_f32_16x16x32_bf16(
                    a_cur[tm], w_cur[te], acc[tm][te], 0, 0, 0);
        a_cur[0] = a_nxt[0]; a_cur[1] = a_nxt[1];
        w_cur[0] = w_nxt[0]; w_cur[1] = w_nxt[1]; w_cur[2] = w_nxt[2]; w_cur[3] = w_nxt[3];
        pa += 9216; pw += 1024;
    }

    size_t obase = (size_t)b * 589824;
    #pragma unroll
    for (int te = 0; te < 4; ++te) {
        int e = e0 + te * 16 + l15;
        float bias = vb[e];
        #pragma unroll
        for (int tm = 0; tm < 2; ++tm) {
            int m = m0 + tm * 16 + quad * 4;
            float4 v;
            v.x = acc[tm][te][0] + bias;
            v.y = acc[tm][te][1] + bias;
            v.z = acc[tm][te][2] + bias;
            v.w = acc[tm][te][3] + bias;
            *(float4*)(out + obase + (size_t)e * 2304 + m) = v;
        }
    }
}

// ---------------------------------------------------------------------------
extern "C" void kernel_launch(void* const* d_in, const int* in_sizes, int n_in,
                              void* d_out, int out_size, void* d_ws, size_t ws_size,
                              hipStream_t stream) {
    const float* hs      = (const float*)d_in[0];
    const float* centers = (const float*)d_in[1];
    const float* spreads = (const float*)d_in[2];
    const float* Wv      = (const float*)d_in[3];
    const float* vbias   = (const float*)d_in[4];

    float* out   = (float*)d_out;
    float* probs = out + OUT0;                   // 47,775,744 floats (191 MB)

    // Scratch placement: prefer d_ws (fill evidence says ~840 MB); else fall
    // back to carving the probs output region (then probs must be written last).
    const size_t need = 98973696;                // bytes
    bool big = ws_size >= need;

    unsigned short *AF, *WF, *hsb, *p1b, *p2b;
    float *p1, *p2;
    if (big) {
        unsigned short* w = (unsigned short*)d_ws;
        AF  = w;                       // 42,467,328 bf16 (84.9 MB)
        WF  = AF + 42467328;           // 589,824 bf16
        hsb = WF + 589824;             // 6,291,456 bf16
        p1b = hsb + 6291456;           // 27,648 bf16
        p2b = p1b + 27648;
        p1  = (float*)(p2b + 27648);   // 20,736 f32 each
        p2  = p1 + 20736;
    } else {
        p1  = (float*)d_ws;
        p2  = p1 + 20736;
        p1b = (unsigned short*)(p2 + 20736);
        p2b = p1b + 27648;
        AF  = (unsigned short*)probs;
        WF  = AF + 42467328;
        hsb = WF + 589824;
    }

    k_pre<<<2444, 256, 0, stream>>>(centers, spreads, hs, Wv, p1, p2, p1b, p2b, hsb, WF);
    if (big) {
        // probs writer overlaps attn compute; scratch doesn't alias probs.
        k_attn_probs<<<2304 + 2592, 256, 0, stream>>>(hsb, p1b, p2b, AF, p1, p2, probs, 2304);
        k_gemmC<<<576, 256, 0, stream>>>(AF, WF, vbias, out);
    } else {
        k_attn_probs<<<2304, 256, 0, stream>>>(hsb, p1b, p2b, AF, p1, p2, probs, 2304);
        k_gemmC<<<576, 256, 0, stream>>>(AF, WF, vbias, out);
        k_attn_probs<<<2592, 256, 0, stream>>>(hsb, p1b, p2b, AF, p1, p2, probs, 0);
    }
}